// Round 13
// baseline (3779.917 us; speedup 1.0000x reference)
//
#include <hip/hip_runtime.h>
#include <hip/hip_bf16.h>
#include <cstdint>

// Problem constants
#define B_   1024
#define V_   16
#define NH_  32
#define SH_  8
#define D_   128
#define KV_  1024
#define H_   4096

typedef __bf16 bf16;
typedef bf16  bf16x8 __attribute__((ext_vector_type(8)));
typedef float f32x2  __attribute__((ext_vector_type(2)));
typedef float f32x4  __attribute__((ext_vector_type(4)));

#define VMCNT(n) asm volatile("s_waitcnt vmcnt(" #n ")" ::: "memory")
#define LGKM0()  asm volatile("s_waitcnt lgkmcnt(0)" ::: "memory")

// async global->LDS, 16B per lane. LDS dest is wave-uniform base + lane*16.
__device__ __forceinline__ void gl2lds16(const void* g, void* l) {
    __builtin_amdgcn_global_load_lds((const __attribute__((address_space(1))) void*)g,
                                     (__attribute__((address_space(3))) void*)l,
                                     16, 0, 0);
}

// ---------------------------------------------------------------------------
// K1: h1[m][v][b][k] = tanh(prefix[b][v] * W1m[v][k] + b1m[v][k])  (bf16)
// ---------------------------------------------------------------------------
__global__ __launch_bounds__(256)
void h1_kernel(const float* __restrict__ prefix,
               const float* __restrict__ W1a, const float* __restrict__ b1a,
               const float* __restrict__ W1b, const float* __restrict__ b1b,
               bf16* __restrict__ h1)
{
    int gid = blockIdx.x * 256 + threadIdx.x;   // 2*V*B*KV/8 = 4M threads
    int k8  = gid & 127;                        // KV_/8 = 128
    int b   = (gid >> 7) & 1023;
    int vm  = gid >> 17;                        // 0..31
    int v   = vm & 15;
    const float* W1 = (vm >> 4) ? W1b : W1a;
    const float* b1 = (vm >> 4) ? b1b : b1a;
    float x = prefix[b * V_ + v];
    const float* wp = W1 + (size_t)v * KV_ + k8 * 8;
    const float* bp = b1 + (size_t)v * KV_ + k8 * 8;
    f32x4 w0 = *(const f32x4*)wp,       w1 = *(const f32x4*)(wp + 4);
    f32x4 q0 = *(const f32x4*)bp,       q1 = *(const f32x4*)(bp + 4);
    bf16x8 o;
#pragma unroll
    for (int j = 0; j < 4; ++j) o[j]     = (bf16)tanhf(fmaf(x, w0[j], q0[j]));
#pragma unroll
    for (int j = 0; j < 4; ++j) o[4 + j] = (bf16)tanhf(fmaf(x, w1[j], q1[j]));
    *(bf16x8*)(h1 + (size_t)gid * 8) = o;
}

// ---------------------------------------------------------------------------
// K2: pipelined GEMM, fused B-transpose+fp32->bf16, both m in one launch.
//   C[m][v] = A_m[v] (1024 x KDIM bf16) * Bf_m[v] ([KDIM][NDIM] fp32)
// MODE 0: tanh(C+bias) -> bf16 h2, LDS-transposed full-line NT stores.
// MODE 1: C+bias -> fp32 scatter to [B,NH,V,D] (+m), 4-way head rep,
//         LDS-transposed 128B-contiguous NT stores.
//
// Round-13 change: 512x256 tile, BK=32, 1024 threads / 16 waves (4m x 4n),
// 128x64 out/wave, acc[8][4]. Halves B re-reads (NMB 4->2): per-v request
// volume 96->64 MB in both GEMMs (the ~7.5 TB/s L2/L3 service rate is the
// binding constraint). Occupancy doubles too: 4 waves/SIMD (was 2).
// LDS: A dbuf 2x32K at [0,64K), B dbuf 2x16K at [64K,96K); 128K declared
// for epilogue scratch (two 8-wave phases x 16KB).
// Steady step kt: loadBR(kt+1)[8 scalar] | stageA(kt+1)[2 gl2lds] | MFMA(kt)
//   [32 MFMA] | VMCNT(2) retire br | writeB(kt+1) | VMCNT(0) | LGKM0 | bar.
// ---------------------------------------------------------------------------
template<int MODE, int KDIM, int NDIM>
__global__ __launch_bounds__(1024)
void gemm_t3(const bf16* __restrict__ A0, const bf16* __restrict__ A1,
             const float* __restrict__ Bf0, const float* __restrict__ Bf1,
             const float* __restrict__ bias0, const float* __restrict__ bias1,
             bf16* __restrict__ outB0, bf16* __restrict__ outB1,
             float* __restrict__ outF)
{
    __shared__ __align__(16) char smem[131072];

    constexpr int NX  = NDIM / 256;     // n-blocks per v
    constexpr int NMB = 2;              // m-blocks per v (512-row tiles)
    constexpr int NXY = NX * NMB;
    const int lin = blockIdx.x + NX * blockIdx.y + NXY * blockIdx.z;
    constexpr int NWG = NXY * 32;       // both m
    constexpr int CHK = NWG / 8;        // NWG % 8 == 0 (bijective swizzle)
    const int swz = (lin & 7) * CHK + (lin >> 3);
    const int mm  = swz / (NXY * 16);           // encoder index 0/1
    const int r2  = swz - mm * (NXY * 16);
    const int v   = r2 / NXY;
    const int rem = r2 - v * NXY;
    const int m0  = (rem / NX) * 512;           // m slower than n (R9)
    const int n0  = (rem - (rem / NX) * NX) * 256;

    const bf16*  Abase = mm ? A1 : A0;
    const float* Bbase = mm ? Bf1 : Bf0;
    const float* bias  = mm ? bias1 : bias0;

    const int t  = threadIdx.x;
    const int l  = t & 63;
    const int w  = t >> 6;          // wave id 0..15
    const int wr = w >> 2;          // wave row 0..3 (128 rows each)
    const int wc = w & 3;           // wave col 0..3 (64 cols each)
    constexpr int NT = KDIM / 32;
    static_assert(NT >= 4, "NT >= 4");

    const bf16*  Av = Abase + (size_t)v * 1024 * KDIM + (size_t)m0 * KDIM;
    const float* Bv = Bbase + (size_t)v * KDIM * NDIM + n0;

    f32x4 acc[8][4];
#pragma unroll
    for (int i = 0; i < 8; ++i)
#pragma unroll
        for (int j = 0; j < 4; ++j) acc[i][j] = f32x4{0.f, 0.f, 0.f, 0.f};

    // B staging: thread t covers n = t&255, k-rows bkg*8..+7 within the step
    const int bn  = t & 255;
    const int bkg = t >> 8;             // 0..3
    const float* bptr = Bv + (size_t)(bkg * 8) * NDIM + bn;
    float br[8];

    auto loadBR = [&](int ktile) {
        const float* np = bptr + (size_t)ktile * 32 * NDIM;
#pragma unroll
        for (int j = 0; j < 8; ++j) br[j] = np[(size_t)j * NDIM];
    };
    auto stageA = [&](int ktile, int ab) {
#pragma unroll
        for (int i = 0; i < 2; ++i) {
            const int off = t + i * 1024;           // 0..2047 (16B chunks)
            const int row = off >> 2;               // 0..511
            const int gc  = (off & 3) ^ ((row >> 1) & 3);
            gl2lds16(Av + (size_t)row * KDIM + ktile * 32 + gc * 8,
                     smem + (size_t)ab * 32768 + (size_t)off * 16);
        }
    };
    auto writeB = [&](int bb) {
        bf16x8 pk;
#pragma unroll
        for (int j = 0; j < 8; ++j) pk[j] = (bf16)br[j];
        const int ch = bkg ^ ((bn >> 1) & 3);       // swizzled chunk slot
        *(bf16x8*)(smem + 65536 + (size_t)bb * 16384
                   + (size_t)bn * 64 + ch * 16) = pk;
    };
    auto mfmaStep = [&](int kt) {
        const bf16* aC = (const bf16*)(smem + (size_t)(kt & 1) * 32768);
        const bf16* bC = (const bf16*)(smem + 65536 + (size_t)(kt & 1) * 16384);
        const int kg = l >> 4;                      // k-group 0..3
        bf16x8 bfv[4];
#pragma unroll
        for (int f = 0; f < 4; ++f) {
            const int nr = wc * 64 + f * 16 + (l & 15);
            const int cb = kg ^ ((nr >> 1) & 3);
            bfv[f] = *(const bf16x8*)(bC + (size_t)nr * 32 + cb * 8);
        }
#pragma unroll
        for (int half = 0; half < 2; ++half) {      // af in two 4-reg halves
            bf16x8 af[4];
#pragma unroll
            for (int f = 0; f < 4; ++f) {
                const int mr = wr * 128 + (half * 4 + f) * 16 + (l & 15);
                const int ca = kg ^ ((mr >> 1) & 3);
                af[f] = *(const bf16x8*)(aC + (size_t)mr * 32 + ca * 8);
            }
#pragma unroll
            for (int f = 0; f < 4; ++f)
#pragma unroll
                for (int fn = 0; fn < 4; ++fn)
                    acc[half * 4 + f][fn] = __builtin_amdgcn_mfma_f32_16x16x32_bf16(
                        af[f], bfv[fn], acc[half * 4 + f][fn], 0, 0, 0);
        }
    };

    // ---- prologue: stage tile 0 ----
    loadBR(0);
    stageA(0, 0);
    VMCNT(2);                       // retire br(0); A(0) still flying
    writeB(0);
    VMCNT(0);                       // A(0) done
    LGKM0();
    __builtin_amdgcn_s_barrier();

    // ---- main loop ----
    for (int kt = 0; kt < NT - 1; ++kt) {
        loadBR(kt + 1);                 // 8 loads, fly under MFMA
        stageA(kt + 1, (kt + 1) & 1);   // 2 gl2lds, fly under MFMA
        mfmaStep(kt);                   // 32 MFMAs
        VMCNT(2);                       // retire br(kt+1); A(kt+1) may fly
        writeB((kt + 1) & 1);
        VMCNT(0);                       // A(kt+1) done
        LGKM0();
        __builtin_amdgcn_s_barrier();   // publish tiles kt+1
    }
    mfmaStep(NT - 1);                   // last step: compute only

    // ---- epilogue. C/D frag: col = lane&15, row = (lane>>4)*4 + reg ----
    // Two 8-wave phases share 8 x 16KB LDS scratch (full 128K declared).
    const int rbase = (l >> 4) * 4;
    const int cbase = l & 15;
    if (MODE == 0) {
        bf16* outB = mm ? outB1 : outB0;
        auto epi = [&](bf16* scr) {
            // scr [128][64] bf16, swizzle c ^ ((r>>2)&3)<<4: conflict-free.
#pragma unroll
            for (int fn = 0; fn < 4; ++fn) {
                const int c  = fn * 16 + cbase;          // 0..63
                const float bv = bias[(size_t)v * NDIM + n0 + wc * 64 + c];
#pragma unroll
                for (int fm = 0; fm < 8; ++fm)
#pragma unroll
                    for (int j = 0; j < 4; ++j) {
                        const int r = fm * 16 + rbase + j;
                        scr[r * 64 + (c ^ (((r >> 2) & 3) << 4))] =
                            (bf16)tanhf(acc[fm][fn][j] + bv);
                    }
            }
            const int c8 = (l & 7) * 8;
#pragma unroll
            for (int i = 0; i < 16; ++i) {
                const int r  = i * 8 + (l >> 3);
                bf16x8 val = *(const bf16x8*)&scr[r * 64 + (c8 ^ (((r >> 2) & 3) << 4))];
                const int mr = m0 + wr * 128 + r;
                const int nc = n0 + wc * 64 + c8;
                __builtin_nontemporal_store(val,
                    (bf16x8*)(outB + (size_t)v * 1024 * NDIM + (size_t)mr * NDIM + nc));
            }
        };
        __syncthreads();
        if (w < 8) epi((bf16*)(smem + (size_t)(w & 7) * 16384));
        __syncthreads();
        if (w >= 8) epi((bf16*)(smem + (size_t)(w & 7) * 16384));
    } else {
        float* outm = outF + (size_t)mm * ((size_t)B_ * NH_ * V_ * D_);
        auto epi = [&](float* scr) {
            const int nb = n0 + wc * 64;     // wave col base (mult of 64)
            const int sh = nb >> 7;          // slider head
            const int db = nb & 127;         // 0 or 64
#pragma unroll
            for (int p = 0; p < 2; ++p) {
#pragma unroll
                for (int fm = 0; fm < 8; ++fm)
#pragma unroll
                    for (int fq = 0; fq < 2; ++fq) {
                        const int fn = 2 * p + fq;
#pragma unroll
                        for (int j = 0; j < 4; ++j) {
                            const int r = fm * 16 + rbase + j;
                            const int c = fq * 16 + cbase;      // 0..31
                            scr[r * 32 + (c ^ (((r >> 2) & 1) << 4))] = acc[fm][fn][j];
                        }
                    }
                const int c4   = (l & 7) * 4;
                const int colg = p * 32 + c4;
                f32x4 bv4;
#pragma unroll
                for (int q = 0; q < 4; ++q)
                    bv4[q] = bias[(size_t)v * NDIM + nb + colg + q];
#pragma unroll
                for (int i = 0; i < 16; ++i) {
                    const int r = i * 8 + (l >> 3);
                    f32x4 val = *(const f32x4*)&scr[r * 32 + (c4 ^ (((r >> 2) & 1) << 4))];
#pragma unroll
                    for (int q = 0; q < 4; ++q) val[q] += bv4[q];
                    const int mr = m0 + wr * 128 + r;
                    float* pp = outm + (size_t)mr * (NH_ * V_ * D_)
                                     + (size_t)(sh * 4) * (V_ * D_)
                                     + (size_t)v * D_ + db + colg;
                    __builtin_nontemporal_store(val, (f32x4*)(pp));
                    __builtin_nontemporal_store(val, (f32x4*)(pp + V_ * D_));
                    __builtin_nontemporal_store(val, (f32x4*)(pp + 2 * V_ * D_));
                    __builtin_nontemporal_store(val, (f32x4*)(pp + 3 * V_ * D_));
                }
            }
        };
        __syncthreads();
        if (w < 8) epi((float*)(smem + (size_t)(w & 7) * 16384));
        __syncthreads();
        if (w >= 8) epi((float*)(smem + (size_t)(w & 7) * 16384));
    }
}

// ---------------------------------------------------------------------------
__global__ void tail_kernel(const float* __restrict__ af, float* __restrict__ out)
{
    out[0] = af[0];
}

// ---------------------------------------------------------------------------
extern "C" void kernel_launch(void* const* d_in, const int* in_sizes, int n_in,
                              void* d_out, int out_size, void* d_ws, size_t ws_size,
                              hipStream_t stream)
{
    const float* prefix = (const float*)d_in[0];
    const float* W1[2]  = {(const float*)d_in[1], (const float*)d_in[7]};
    const float* b1[2]  = {(const float*)d_in[2], (const float*)d_in[8]};
    const float* W2[2]  = {(const float*)d_in[3], (const float*)d_in[9]};
    const float* b2[2]  = {(const float*)d_in[4], (const float*)d_in[10]};
    const float* W3[2]  = {(const float*)d_in[5], (const float*)d_in[11]};
    const float* b3[2]  = {(const float*)d_in[6], (const float*)d_in[12]};
    const float* afac   = (const float*)d_in[13];

    // workspace: h1[2] = 2x32MiB, h2[2] = 2x128MiB  (ws is ~2.1 GB)
    bf16* h1  = (bf16*)d_ws;                                   // [m][v][b][k]
    bf16* h2a = (bf16*)((char*)d_ws + (size_t)67108864);
    bf16* h2b = (bf16*)((char*)d_ws + (size_t)67108864 + (size_t)134217728);
    float* outp = (float*)d_out;

    // h1 for both encoders
    h1_kernel<<<16384, 256, 0, stream>>>(prefix, W1[0], b1[0], W1[1], b1[1], h1);
    // h2 = tanh(h1 @ W2 + b2), both m in one 1024-block launch
    gemm_t3<0, 1024, 4096><<<dim3(16, 2, 32), 1024, 0, stream>>>(
        h1, h1 + (size_t)16777216, W2[0], W2[1], b2[0], b2[1],
        h2a, h2b, nullptr);
    // out = h2 @ W3 + b3, keys+values in one 256-block launch (1/CU)
    gemm_t3<1, 4096, 1024><<<dim3(4, 2, 32), 1024, 0, stream>>>(
        h2a, h2b, W3[0], W3[1], b3[0], b3[1],
        nullptr, nullptr, outp);
    tail_kernel<<<1, 1, 0, stream>>>(afac, outp + (size_t)2 * B_ * NH_ * V_ * D_);
}

// Round 14
// 2338.741 us; speedup vs baseline: 1.6162x; 1.6162x over previous
//
#include <hip/hip_runtime.h>
#include <hip/hip_bf16.h>
#include <cstdint>

// Problem constants
#define B_   1024
#define V_   16
#define NH_  32
#define SH_  8
#define D_   128
#define KV_  1024
#define H_   4096

typedef __bf16 bf16;
typedef bf16  bf16x8 __attribute__((ext_vector_type(8)));
typedef float f32x2  __attribute__((ext_vector_type(2)));
typedef float f32x4  __attribute__((ext_vector_type(4)));

#define VMCNT(n) asm volatile("s_waitcnt vmcnt(" #n ")" ::: "memory")
#define LGKM0()  asm volatile("s_waitcnt lgkmcnt(0)" ::: "memory")

// async global->LDS, 16B per lane. LDS dest is wave-uniform base + lane*16.
__device__ __forceinline__ void gl2lds16(const void* g, void* l) {
    __builtin_amdgcn_global_load_lds((const __attribute__((address_space(1))) void*)g,
                                     (__attribute__((address_space(3))) void*)l,
                                     16, 0, 0);
}

// ---------------------------------------------------------------------------
// K1: h1[m][v][b][k] = tanh(prefix[b][v] * W1m[v][k] + b1m[v][k])  (bf16)
// ---------------------------------------------------------------------------
__global__ __launch_bounds__(256)
void h1_kernel(const float* __restrict__ prefix,
               const float* __restrict__ W1a, const float* __restrict__ b1a,
               const float* __restrict__ W1b, const float* __restrict__ b1b,
               bf16* __restrict__ h1)
{
    int gid = blockIdx.x * 256 + threadIdx.x;   // 2*V*B*KV/8 = 4M threads
    int k8  = gid & 127;                        // KV_/8 = 128
    int b   = (gid >> 7) & 1023;
    int vm  = gid >> 17;                        // 0..31
    int v   = vm & 15;
    const float* W1 = (vm >> 4) ? W1b : W1a;
    const float* b1 = (vm >> 4) ? b1b : b1a;
    float x = prefix[b * V_ + v];
    const float* wp = W1 + (size_t)v * KV_ + k8 * 8;
    const float* bp = b1 + (size_t)v * KV_ + k8 * 8;
    f32x4 w0 = *(const f32x4*)wp,       w1 = *(const f32x4*)(wp + 4);
    f32x4 q0 = *(const f32x4*)bp,       q1 = *(const f32x4*)(bp + 4);
    bf16x8 o;
#pragma unroll
    for (int j = 0; j < 4; ++j) o[j]     = (bf16)tanhf(fmaf(x, w0[j], q0[j]));
#pragma unroll
    for (int j = 0; j < 4; ++j) o[4 + j] = (bf16)tanhf(fmaf(x, w1[j], q1[j]));
    *(bf16x8*)(h1 + (size_t)gid * 8) = o;
}

// ---------------------------------------------------------------------------
// K2: pipelined GEMM, fused B-transpose+fp32->bf16, both m in one launch.
//   C[m][v] = A_m[v] (1024 x KDIM bf16) * Bf_m[v] ([KDIM][NDIM] fp32)
// MODE 0: tanh(C+bias) -> bf16 h2, LDS-transposed full-line NT stores.
// MODE 1: C+bias -> fp32 scatter to [B,NH,V,D] (+m), 4-way head rep,
//         LDS-transposed 128B-contiguous NT stores.
//
// R12 geometry (proven 867us): 256x256 tile, 512 thr, 8 waves (2m x 4n),
// 128x64 out/wave, acc[8][4], BK=64, LDS 128K (A dbuf 2x32K, B dbuf 2x32K),
// 1 block/CU. R9 decode: XCD-chunked bijective swizzle, m-index slowest.
//
// Round-14 change (R6-proven counted-vmcnt, recounted for this geometry):
// br staged TWO steps ahead in 2 register banks so no load in the steady
// loop is waited on in the step it was issued:
//   entry invariant: br(kt+1)[16] in flight (in bankUse)
//   stageA(kt+1)[4] | loadBR(kt+2)->bankIss[16] | setprio1 MFMA setprio0
//   | VMCNT(20) retire br(kt+1) | writeB(bankUse) | VMCNT(16) retire A(kt+1)
//   | LGKM0 | s_barrier.   No vmcnt(0) until the tail.
// __launch_bounds__(512,2): VGPR budget 256 (R13's spill guard; ~155 used).
// ---------------------------------------------------------------------------
template<int MODE, int KDIM, int NDIM>
__global__ __launch_bounds__(512, 2)
void gemm_t4(const bf16* __restrict__ A0, const bf16* __restrict__ A1,
             const float* __restrict__ Bf0, const float* __restrict__ Bf1,
             const float* __restrict__ bias0, const float* __restrict__ bias1,
             bf16* __restrict__ outB0, bf16* __restrict__ outB1,
             float* __restrict__ outF)
{
    // aBuf: 2 x 32KB at [0, 65536); bBuf: 2 x 32KB at [65536, 131072)
    __shared__ __align__(16) char smem[131072];

    constexpr int NX  = NDIM / 256;     // n-blocks per v
    constexpr int NMB = 4;              // m-blocks per v
    constexpr int NXY = NX * NMB;       // blocks per v
    const int lin = blockIdx.x + NX * blockIdx.y + NXY * blockIdx.z;
    constexpr int NWG = NXY * 32;       // both m
    constexpr int CHK = NWG / 8;        // NWG % 8 == 0 (bijective swizzle)
    const int swz = (lin & 7) * CHK + (lin >> 3);
    const int mm  = swz / (NXY * 16);           // encoder index 0/1
    const int r2  = swz - mm * (NXY * 16);
    const int v   = r2 / NXY;
    const int rem = r2 - v * NXY;
    const int m0  = (rem / NX) * 256;           // m slower than n (R9)
    const int n0  = (rem - (rem / NX) * NX) * 256;

    const bf16*  Abase = mm ? A1 : A0;
    const float* Bbase = mm ? Bf1 : Bf0;
    const float* bias  = mm ? bias1 : bias0;

    const int t  = threadIdx.x;
    const int l  = t & 63;
    const int w  = t >> 6;          // wave id 0..7
    const int wr = w >> 2;          // wave row 0..1 (128 rows each)
    const int wc = w & 3;           // wave col 0..3 (64 cols each)
    constexpr int NT = KDIM / 64;
    static_assert(NT >= 4 && (NT % 2) == 0, "NT even, >= 4");

    const bf16*  Av = Abase + (size_t)v * 1024 * KDIM + (size_t)m0 * KDIM;
    const float* Bv = Bbase + (size_t)v * KDIM * NDIM + n0;

    f32x4 acc[8][4];
#pragma unroll
    for (int i = 0; i < 8; ++i)
#pragma unroll
        for (int j = 0; j < 4; ++j) acc[i][j] = f32x4{0.f, 0.f, 0.f, 0.f};

    // B staging: thread t covers n = 2*(t&127)+{0,1}, k-rows (t>>7)*16..+15
    const float* bptr = Bv + (size_t)((t >> 7) * 16) * NDIM + 2 * (t & 127);
    f32x2 brA[16], brB[16];

    auto loadBR = [&](int ktile, f32x2 (&bank)[16]) {
        const float* np = bptr + (size_t)ktile * 64 * NDIM;
#pragma unroll
        for (int j = 0; j < 16; ++j) bank[j] = *(const f32x2*)(np + (size_t)j * NDIM);
    };
    auto stageA = [&](int ktile, int ab) {
#pragma unroll
        for (int i = 0; i < 4; ++i) {
            const int off = t + i * 512;            // 0..2047 (16B chunks)
            const int row = off >> 3;               // 0..255
            const int gc  = (off & 7) ^ ((row >> 1) & 7);
            gl2lds16(Av + (size_t)row * KDIM + ktile * 64 + gc * 8,
                     smem + (size_t)ab * 32768 + (size_t)off * 16);
        }
    };
    auto writeB = [&](f32x2 (&bank)[16], int bb) {
        bf16* bN = (bf16*)(smem + 65536 + (size_t)bb * 32768);
#pragma unroll
        for (int i = 0; i < 2; ++i)
#pragma unroll
            for (int h = 0; h < 2; ++h) {
                bf16x8 pk;
#pragma unroll
                for (int jj = 0; jj < 8; ++jj) pk[jj] = (bf16)bank[h * 8 + jj][i];
                const int n  = 2 * (t & 127) + i;               // 0..255
                const int ch = ((t >> 7) * 2 + h) ^ (t & 7);    // swizzled slot
                *(bf16x8*)(bN + (size_t)n * 64 + ch * 8) = pk;
            }
    };
    auto mfmaStep = [&](int kt) {
        const bf16* aC = (const bf16*)(smem + (size_t)(kt & 1) * 32768);
        const bf16* bC = (const bf16*)(smem + 65536 + (size_t)(kt & 1) * 32768);
        __builtin_amdgcn_s_setprio(1);
#pragma unroll
        for (int kk = 0; kk < 2; ++kk) {
            bf16x8 af[8], bfv[4];
#pragma unroll
            for (int f = 0; f < 8; ++f) {
                const int mr = wr * 128 + f * 16 + (l & 15);
                const int ca = (kk * 4 + (l >> 4)) ^ ((mr >> 1) & 7);
                af[f] = *(const bf16x8*)(aC + (size_t)mr * 64 + ca * 8);
            }
#pragma unroll
            for (int f = 0; f < 4; ++f) {
                const int nr = wc * 64 + f * 16 + (l & 15);
                const int cb = (kk * 4 + (l >> 4)) ^ ((nr >> 1) & 7);
                bfv[f] = *(const bf16x8*)(bC + (size_t)nr * 64 + cb * 8);
            }
#pragma unroll
            for (int fm = 0; fm < 8; ++fm)
#pragma unroll
                for (int fn = 0; fn < 4; ++fn)
                    acc[fm][fn] = __builtin_amdgcn_mfma_f32_16x16x32_bf16(
                        af[fm], bfv[fn], acc[fm][fn], 0, 0, 0);
        }
        __builtin_amdgcn_s_setprio(0);
    };

    // ---- prologue: establish invariant (entry kt: br(kt+1) in flight) ----
    loadBR(0, brA);               // br(0) [16]
    stageA(0, 0);                 // A(0)  [4]   outstanding 20
    loadBR(1, brB);               // br(1) [16]  outstanding 36
    VMCNT(20);                    // retire br(0); keep A(0)+br(1)
    writeB(brA, 0);               // B(0) -> bBuf0
    VMCNT(16);                    // retire A(0); br(1) stays out
    LGKM0();
    __builtin_amdgcn_s_barrier(); // tile 0 published

    // ---- steady loop, unrolled by 2 for static bank selection ----
    auto stepS = [&](int kt, f32x2 (&brIss)[16], f32x2 (&brUse)[16]) {
        stageA(kt + 1, (kt + 1) & 1);   // A(kt+1) [4]
        loadBR(kt + 2, brIss);          // br(kt+2) [16]; outstanding 36
        mfmaStep(kt);                   // loads fly under 64 MFMAs
        VMCNT(20);                      // retire br(kt+1); keep A(kt+1)+br(kt+2)
        writeB(brUse, (kt + 1) & 1);    // B(kt+1) -> bBuf[nxt]
        VMCNT(16);                      // retire A(kt+1); br(kt+2) stays out
        LGKM0();
        __builtin_amdgcn_s_barrier();   // publish tiles kt+1
    };
    for (int kt = 0; kt + 3 < NT; kt += 2) {
        stepS(kt,     brA, brB);
        stepS(kt + 1, brB, brA);
    }
    {   // penultimate step kt = NT-2: entry in-flight br(NT-1)[16] in brB
        stageA(NT - 1, (NT - 1) & 1);   // outstanding 20
        mfmaStep(NT - 2);
        VMCNT(4);                       // retire br(NT-1); keep A(NT-1)
        writeB(brB, (NT - 1) & 1);
        VMCNT(0);                       // retire A(NT-1)
        LGKM0();
        __builtin_amdgcn_s_barrier();
    }
    mfmaStep(NT - 1);                   // last step: compute only

    // ---- epilogue. C/D frag: col = lane&15, row = (lane>>4)*4 + reg ----
    const int rbase = (l >> 4) * 4;
    const int cbase = l & 15;
    if (MODE == 0) {
        bf16* outB = mm ? outB1 : outB0;
        __syncthreads();   // main-loop LDS reads done before scratch reuse
        // per-wave 128x64 bf16 scratch (16KB x 8 = 128KB). Write swizzled
        // (c ^ ((r>>2)&3)<<4): conflict-free. Read 8 consecutive cols/lane
        // -> 8 lanes cover a full 128B row -> full-line NT stores.
        bf16* scr = (bf16*)(smem + (size_t)w * 16384);   // [128][64]
#pragma unroll
        for (int fn = 0; fn < 4; ++fn) {
            const int c  = fn * 16 + cbase;              // 0..63
            const float bv = bias[(size_t)v * NDIM + n0 + wc * 64 + c];
#pragma unroll
            for (int fm = 0; fm < 8; ++fm)
#pragma unroll
                for (int j = 0; j < 4; ++j) {
                    const int r = fm * 16 + rbase + j;   // 0..127
                    scr[r * 64 + (c ^ (((r >> 2) & 3) << 4))] =
                        (bf16)tanhf(acc[fm][fn][j] + bv);
                }
        }
        const int c8 = (l & 7) * 8;                      // lane's 8-col group
#pragma unroll
        for (int i = 0; i < 16; ++i) {
            const int r  = i * 8 + (l >> 3);             // 0..127
            bf16x8 val = *(const bf16x8*)&scr[r * 64 + (c8 ^ (((r >> 2) & 3) << 4))];
            const int mr = m0 + wr * 128 + r;
            const int nc = n0 + wc * 64 + c8;
            __builtin_nontemporal_store(val,
                (bf16x8*)(outB + (size_t)v * 1024 * NDIM + (size_t)mr * NDIM + nc));
        }
    } else {
        float* outm = outF + (size_t)mm * ((size_t)B_ * NH_ * V_ * D_);
        __syncthreads();   // main-loop LDS reads done before scratch reuse
        // per-wave 128x32 f32 scratch (16KB x 8 waves = 128KB), two 32-col
        // passes; swizzle (c ^ ((r>>2)&1)<<4): write 2-way (free), read full.
        float* scr = (float*)(smem + (size_t)w * 16384);
        const int nb = n0 + wc * 64;     // wave col base (multiple of 64)
        const int sh = nb >> 7;          // slider head
        const int db = nb & 127;         // 0 or 64
#pragma unroll
        for (int p = 0; p < 2; ++p) {
#pragma unroll
            for (int fm = 0; fm < 8; ++fm)
#pragma unroll
                for (int fq = 0; fq < 2; ++fq) {
                    const int fn = 2 * p + fq;
#pragma unroll
                    for (int j = 0; j < 4; ++j) {
                        const int r = fm * 16 + rbase + j;      // 0..127
                        const int c = fq * 16 + cbase;          // 0..31
                        scr[r * 32 + (c ^ (((r >> 2) & 1) << 4))] = acc[fm][fn][j];
                    }
                }
            const int c4   = (l & 7) * 4;
            const int colg = p * 32 + c4;    // col within wave's 64-col strip
            f32x4 bv4;
#pragma unroll
            for (int q = 0; q < 4; ++q)
                bv4[q] = bias[(size_t)v * NDIM + nb + colg + q];
#pragma unroll
            for (int i = 0; i < 16; ++i) {
                const int r = i * 8 + (l >> 3);                 // 0..127
                f32x4 val = *(const f32x4*)&scr[r * 32 + (c4 ^ (((r >> 2) & 1) << 4))];
#pragma unroll
                for (int q = 0; q < 4; ++q) val[q] += bv4[q];
                const int mr = m0 + wr * 128 + r;
                float* pp = outm + (size_t)mr * (NH_ * V_ * D_)
                                 + (size_t)(sh * 4) * (V_ * D_)
                                 + (size_t)v * D_ + db + colg;
                __builtin_nontemporal_store(val, (f32x4*)(pp));
                __builtin_nontemporal_store(val, (f32x4*)(pp + V_ * D_));
                __builtin_nontemporal_store(val, (f32x4*)(pp + 2 * V_ * D_));
                __builtin_nontemporal_store(val, (f32x4*)(pp + 3 * V_ * D_));
            }
        }
    }
}

// ---------------------------------------------------------------------------
__global__ void tail_kernel(const float* __restrict__ af, float* __restrict__ out)
{
    out[0] = af[0];
}

// ---------------------------------------------------------------------------
extern "C" void kernel_launch(void* const* d_in, const int* in_sizes, int n_in,
                              void* d_out, int out_size, void* d_ws, size_t ws_size,
                              hipStream_t stream)
{
    const float* prefix = (const float*)d_in[0];
    const float* W1[2]  = {(const float*)d_in[1], (const float*)d_in[7]};
    const float* b1[2]  = {(const float*)d_in[2], (const float*)d_in[8]};
    const float* W2[2]  = {(const float*)d_in[3], (const float*)d_in[9]};
    const float* b2[2]  = {(const float*)d_in[4], (const float*)d_in[10]};
    const float* W3[2]  = {(const float*)d_in[5], (const float*)d_in[11]};
    const float* b3[2]  = {(const float*)d_in[6], (const float*)d_in[12]};
    const float* afac   = (const float*)d_in[13];

    // workspace: h1[2] = 2x32MiB, h2[2] = 2x128MiB  (ws is ~2.1 GB)
    bf16* h1  = (bf16*)d_ws;                                   // [m][v][b][k]
    bf16* h2a = (bf16*)((char*)d_ws + (size_t)67108864);
    bf16* h2b = (bf16*)((char*)d_ws + (size_t)67108864 + (size_t)134217728);
    float* outp = (float*)d_out;

    // h1 for both encoders
    h1_kernel<<<16384, 256, 0, stream>>>(prefix, W1[0], b1[0], W1[1], b1[1], h1);
    // h2 = tanh(h1 @ W2 + b2), both m in one 2048-block launch
    gemm_t4<0, 1024, 4096><<<dim3(16, 4, 32), 512, 0, stream>>>(
        h1, h1 + (size_t)16777216, W2[0], W2[1], b2[0], b2[1],
        h2a, h2b, nullptr);
    // out = h2 @ W3 + b3, keys+values in one 512-block launch
    gemm_t4<1, 4096, 1024><<<dim3(4, 4, 32), 512, 0, stream>>>(
        h2a, h2b, W3[0], W3[1], b3[0], b3[1],
        nullptr, nullptr, outp);
    tail_kernel<<<1, 1, 0, stream>>>(afac, outp + (size_t)2 * B_ * NH_ * V_ * D_);
}

// Round 15
// 1019.492 us; speedup vs baseline: 3.7076x; 2.2940x over previous
//
#include <hip/hip_runtime.h>
#include <hip/hip_bf16.h>
#include <cstdint>

// Problem constants
#define B_   1024
#define V_   16
#define NH_  32
#define SH_  8
#define D_   128
#define KV_  1024
#define H_   4096

typedef __bf16 bf16;
typedef bf16  bf16x8 __attribute__((ext_vector_type(8)));
typedef float f32x2  __attribute__((ext_vector_type(2)));
typedef float f32x4  __attribute__((ext_vector_type(4)));

#define VMCNT(n) asm volatile("s_waitcnt vmcnt(" #n ")" ::: "memory")
#define LGKM0()  asm volatile("s_waitcnt lgkmcnt(0)" ::: "memory")

// async global->LDS, 16B per lane. LDS dest is wave-uniform base + lane*16.
__device__ __forceinline__ void gl2lds16(const void* g, void* l) {
    __builtin_amdgcn_global_load_lds((const __attribute__((address_space(1))) void*)g,
                                     (__attribute__((address_space(3))) void*)l,
                                     16, 0, 0);
}

// ---------------------------------------------------------------------------
// GEMM1 with FUSED h1 (A-operand computed in-kernel, never materialized):
//   h2[m][v] = tanh( tanh(prefix[:,v] x W1 + b1) @ W2 + b2 )
// 256x256 tile, 512 thr, 8 waves (2m x 4n), 128x64 out/wave, acc[8][4],
// BK=64. A tile (256x64 bf16) computed per step from LDS-staged
// W1/b1/prefix (8KB+1KB, one-time) and ds_written into aBuf dbuf --
// removes the h1 kernel, its 64MB HBM write, and ~1GB of A-panel re-read
// request volume (16 n-blocks re-read each panel).
// Steady step kt: loadBR(kt+1)[16] | computeA(kt+1) (VALU+LDS, br flies)
//   | MFMA(kt) | VMCNT(0) retire br | writeB(kt+1) | LGKM0 | s_barrier.
// ---------------------------------------------------------------------------
__global__ __launch_bounds__(512)
void gemm1_f(const float* __restrict__ prefix,
             const float* __restrict__ W1a, const float* __restrict__ b1a,
             const float* __restrict__ W1b, const float* __restrict__ b1b,
             const float* __restrict__ Bf0, const float* __restrict__ Bf1,
             const float* __restrict__ bias0, const float* __restrict__ bias1,
             bf16* __restrict__ outB0, bf16* __restrict__ outB1)
{
    constexpr int KDIM = 1024, NDIM = 4096;
    // aBuf 2x32K [0,64K) | bBuf 2x32K [64K,128K) | w1 4K | b1 4K | pref 1K
    __shared__ __align__(16) char smem[140288];
    float* w1L = (float*)(smem + 131072);
    float* b1L = (float*)(smem + 135168);
    float* pfL = (float*)(smem + 139264);

    constexpr int NX  = NDIM / 256;     // 16 n-blocks per v
    constexpr int NMB = 4;
    constexpr int NXY = NX * NMB;       // 64
    const int lin = blockIdx.x + NX * blockIdx.y + NXY * blockIdx.z;
    constexpr int NWG = NXY * 32;       // 2048
    constexpr int CHK = NWG / 8;
    const int swz = (lin & 7) * CHK + (lin >> 3);
    const int mm  = swz / (NXY * 16);
    const int r2  = swz - mm * (NXY * 16);
    const int v   = r2 / NXY;
    const int rem = r2 - v * NXY;
    const int m0  = (rem / NX) * 256;
    const int n0  = (rem - (rem / NX) * NX) * 256;

    const float* W1v = (mm ? W1b : W1a) + (size_t)v * KV_;
    const float* b1v = (mm ? b1b : b1a) + (size_t)v * KV_;
    const float* Bv  = (mm ? Bf1 : Bf0) + (size_t)v * KDIM * NDIM + n0;
    const float* bias = mm ? bias1 : bias0;
    bf16* outB = mm ? outB1 : outB0;

    const int t  = threadIdx.x;
    const int l  = t & 63;
    const int w  = t >> 6;
    const int wr = w >> 2;
    const int wc = w & 3;
    constexpr int NT = KDIM / 64;       // 16

    f32x4 acc[8][4];
#pragma unroll
    for (int i = 0; i < 8; ++i)
#pragma unroll
        for (int j = 0; j < 4; ++j) acc[i][j] = f32x4{0.f, 0.f, 0.f, 0.f};

    const float* bptr = Bv + (size_t)((t >> 7) * 16) * NDIM + 2 * (t & 127);
    f32x2 br[16];

    auto loadBR = [&](int ktile) {
        const float* np = bptr + (size_t)ktile * 64 * NDIM;
#pragma unroll
        for (int j = 0; j < 16; ++j) br[j] = *(const f32x2*)(np + (size_t)j * NDIM);
    };
    auto computeA = [&](int ktile, int ab) {
#pragma unroll
        for (int i = 0; i < 4; ++i) {
            const int off = t + i * 512;            // 0..2047 (16B chunks)
            const int row = off >> 3;               // 0..255
            const int gc  = (off & 7) ^ ((row >> 1) & 7);
            const int kb  = ktile * 64 + gc * 8;
            const float x = pfL[row];
            f32x4 wa = *(const f32x4*)&w1L[kb],     wb = *(const f32x4*)&w1L[kb + 4];
            f32x4 qa = *(const f32x4*)&b1L[kb],     qb = *(const f32x4*)&b1L[kb + 4];
            bf16x8 o;
#pragma unroll
            for (int j = 0; j < 4; ++j) o[j]     = (bf16)tanhf(fmaf(x, wa[j], qa[j]));
#pragma unroll
            for (int j = 0; j < 4; ++j) o[4 + j] = (bf16)tanhf(fmaf(x, wb[j], qb[j]));
            *(bf16x8*)(smem + (size_t)ab * 32768 + (size_t)off * 16) = o;
        }
    };
    auto writeB = [&](int bb) {
        bf16* bN = (bf16*)(smem + 65536 + (size_t)bb * 32768);
#pragma unroll
        for (int i = 0; i < 2; ++i)
#pragma unroll
            for (int h = 0; h < 2; ++h) {
                bf16x8 pk;
#pragma unroll
                for (int jj = 0; jj < 8; ++jj) pk[jj] = (bf16)br[h * 8 + jj][i];
                const int n  = 2 * (t & 127) + i;
                const int ch = ((t >> 7) * 2 + h) ^ (t & 7);
                *(bf16x8*)(bN + (size_t)n * 64 + ch * 8) = pk;
            }
    };
    auto mfmaStep = [&](int kt) {
        const bf16* aC = (const bf16*)(smem + (size_t)(kt & 1) * 32768);
        const bf16* bC = (const bf16*)(smem + 65536 + (size_t)(kt & 1) * 32768);
#pragma unroll
        for (int kk = 0; kk < 2; ++kk) {
            bf16x8 af[8], bfv[4];
#pragma unroll
            for (int f = 0; f < 8; ++f) {
                const int mr = wr * 128 + f * 16 + (l & 15);
                const int ca = (kk * 4 + (l >> 4)) ^ ((mr >> 1) & 7);
                af[f] = *(const bf16x8*)(aC + (size_t)mr * 64 + ca * 8);
            }
#pragma unroll
            for (int f = 0; f < 4; ++f) {
                const int nr = wc * 64 + f * 16 + (l & 15);
                const int cb = (kk * 4 + (l >> 4)) ^ ((nr >> 1) & 7);
                bfv[f] = *(const bf16x8*)(bC + (size_t)nr * 64 + cb * 8);
            }
#pragma unroll
            for (int fm = 0; fm < 8; ++fm)
#pragma unroll
                for (int fn = 0; fn < 4; ++fn)
                    acc[fm][fn] = __builtin_amdgcn_mfma_f32_16x16x32_bf16(
                        af[fm], bfv[fn], acc[fm][fn], 0, 0, 0);
        }
    };

    // ---- prologue: stage consts (W1/b1 slices + prefix column) + tile 0 ----
    loadBR(0);                          // br(0) flies under const staging
    if (t < 256) {
        f32x4 wv = *(const f32x4*)(W1v + t * 4);
        float pf = prefix[(size_t)(m0 + t) * V_ + v];
        *(f32x4*)&w1L[t * 4] = wv;
        pfL[t] = pf;
    } else {
        f32x4 qv = *(const f32x4*)(b1v + (t - 256) * 4);
        *(f32x4*)&b1L[(t - 256) * 4] = qv;
    }
    __syncthreads();                    // consts visible; br(0) retired
    computeA(0, 0);
    writeB(0);
    LGKM0();
    __builtin_amdgcn_s_barrier();       // tile 0 published

    // ---- main loop ----
    for (int kt = 0; kt < NT - 1; ++kt) {
        loadBR(kt + 1);                 // 16 loads, fly under computeA+MFMA
        computeA(kt + 1, (kt + 1) & 1); // VALU tanh + LDS, no vmem
        mfmaStep(kt);
        VMCNT(0);                       // retire br(kt+1) (full phase elapsed)
        writeB((kt + 1) & 1);
        LGKM0();
        __builtin_amdgcn_s_barrier();   // publish tiles kt+1
    }
    mfmaStep(NT - 1);

    // ---- epilogue (R12 MODE-0): LDS transpose -> full-line NT stores ----
    const int rbase = (l >> 4) * 4;
    const int cbase = l & 15;
    __syncthreads();
    bf16* scr = (bf16*)(smem + (size_t)w * 16384);   // [128][64]
#pragma unroll
    for (int fn = 0; fn < 4; ++fn) {
        const int c  = fn * 16 + cbase;
        const float bv = bias[(size_t)v * NDIM + n0 + wc * 64 + c];
#pragma unroll
        for (int fm = 0; fm < 8; ++fm)
#pragma unroll
            for (int j = 0; j < 4; ++j) {
                const int r = fm * 16 + rbase + j;
                scr[r * 64 + (c ^ (((r >> 2) & 3) << 4))] =
                    (bf16)tanhf(acc[fm][fn][j] + bv);
            }
    }
    const int c8 = (l & 7) * 8;
#pragma unroll
    for (int i = 0; i < 16; ++i) {
        const int r  = i * 8 + (l >> 3);
        bf16x8 val = *(const bf16x8*)&scr[r * 64 + (c8 ^ (((r >> 2) & 3) << 4))];
        const int mr = m0 + wr * 128 + r;
        const int nc = n0 + wc * 64 + c8;
        __builtin_nontemporal_store(val,
            (bf16x8*)(outB + (size_t)v * 1024 * NDIM + (size_t)mr * NDIM + nc));
    }
}

// ---------------------------------------------------------------------------
// GEMM2 (byte-exact R12 structure, MODE-1 only, de-templated):
//   out = h2 @ W3 + b3 -> fp32 scatter to [B,NH,V,D] (+m), 4-way head rep.
// ---------------------------------------------------------------------------
__global__ __launch_bounds__(512)
void gemm2_k(const bf16* __restrict__ A0, const bf16* __restrict__ A1,
             const float* __restrict__ Bf0, const float* __restrict__ Bf1,
             const float* __restrict__ bias0, const float* __restrict__ bias1,
             float* __restrict__ outF)
{
    constexpr int KDIM = 4096, NDIM = 1024;
    __shared__ __align__(16) char smem[131072];

    constexpr int NX  = NDIM / 256;     // 4
    constexpr int NMB = 4;
    constexpr int NXY = NX * NMB;       // 16
    const int lin = blockIdx.x + NX * blockIdx.y + NXY * blockIdx.z;
    constexpr int NWG = NXY * 32;       // 512
    constexpr int CHK = NWG / 8;
    const int swz = (lin & 7) * CHK + (lin >> 3);
    const int mm  = swz / (NXY * 16);
    const int r2  = swz - mm * (NXY * 16);
    const int v   = r2 / NXY;
    const int rem = r2 - v * NXY;
    const int m0  = (rem / NX) * 256;
    const int n0  = (rem - (rem / NX) * NX) * 256;

    const bf16*  Abase = mm ? A1 : A0;
    const float* Bbase = mm ? Bf1 : Bf0;
    const float* bias  = mm ? bias1 : bias0;

    const int t  = threadIdx.x;
    const int l  = t & 63;
    const int w  = t >> 6;
    const int wr = w >> 2;
    const int wc = w & 3;
    constexpr int NT = KDIM / 64;       // 64

    const bf16*  Av = Abase + (size_t)v * 1024 * KDIM + (size_t)m0 * KDIM;
    const float* Bv = Bbase + (size_t)v * KDIM * NDIM + n0;

    f32x4 acc[8][4];
#pragma unroll
    for (int i = 0; i < 8; ++i)
#pragma unroll
        for (int j = 0; j < 4; ++j) acc[i][j] = f32x4{0.f, 0.f, 0.f, 0.f};

    const float* bptr = Bv + (size_t)((t >> 7) * 16) * NDIM + 2 * (t & 127);
    f32x2 br[16];

    auto loadBR = [&](int ktile) {
        const float* np = bptr + (size_t)ktile * 64 * NDIM;
#pragma unroll
        for (int j = 0; j < 16; ++j) br[j] = *(const f32x2*)(np + (size_t)j * NDIM);
    };
    auto stageA = [&](int ktile, int ab) {
#pragma unroll
        for (int i = 0; i < 4; ++i) {
            const int off = t + i * 512;
            const int row = off >> 3;
            const int gc  = (off & 7) ^ ((row >> 1) & 7);
            gl2lds16(Av + (size_t)row * KDIM + ktile * 64 + gc * 8,
                     smem + (size_t)ab * 32768 + (size_t)off * 16);
        }
    };
    auto writeB = [&](int bb) {
        bf16* bN = (bf16*)(smem + 65536 + (size_t)bb * 32768);
#pragma unroll
        for (int i = 0; i < 2; ++i)
#pragma unroll
            for (int h = 0; h < 2; ++h) {
                bf16x8 pk;
#pragma unroll
                for (int jj = 0; jj < 8; ++jj) pk[jj] = (bf16)br[h * 8 + jj][i];
                const int n  = 2 * (t & 127) + i;
                const int ch = ((t >> 7) * 2 + h) ^ (t & 7);
                *(bf16x8*)(bN + (size_t)n * 64 + ch * 8) = pk;
            }
    };
    auto mfmaStep = [&](int kt) {
        const bf16* aC = (const bf16*)(smem + (size_t)(kt & 1) * 32768);
        const bf16* bC = (const bf16*)(smem + 65536 + (size_t)(kt & 1) * 32768);
#pragma unroll
        for (int kk = 0; kk < 2; ++kk) {
            bf16x8 af[8], bfv[4];
#pragma unroll
            for (int f = 0; f < 8; ++f) {
                const int mr = wr * 128 + f * 16 + (l & 15);
                const int ca = (kk * 4 + (l >> 4)) ^ ((mr >> 1) & 7);
                af[f] = *(const bf16x8*)(aC + (size_t)mr * 64 + ca * 8);
            }
#pragma unroll
            for (int f = 0; f < 4; ++f) {
                const int nr = wc * 64 + f * 16 + (l & 15);
                const int cb = (kk * 4 + (l >> 4)) ^ ((nr >> 1) & 7);
                bfv[f] = *(const bf16x8*)(bC + (size_t)nr * 64 + cb * 8);
            }
#pragma unroll
            for (int fm = 0; fm < 8; ++fm)
#pragma unroll
                for (int fn = 0; fn < 4; ++fn)
                    acc[fm][fn] = __builtin_amdgcn_mfma_f32_16x16x32_bf16(
                        af[fm], bfv[fn], acc[fm][fn], 0, 0, 0);
        }
    };

    // ---- prologue ----
    loadBR(0);
    stageA(0, 0);
    VMCNT(4);
    writeB(0);
    VMCNT(0);
    LGKM0();
    __builtin_amdgcn_s_barrier();

    // ---- main loop ----
    for (int kt = 0; kt < NT - 1; ++kt) {
        loadBR(kt + 1);
        stageA(kt + 1, (kt + 1) & 1);
        mfmaStep(kt);
        VMCNT(4);
        writeB((kt + 1) & 1);
        VMCNT(0);
        LGKM0();
        __builtin_amdgcn_s_barrier();
    }
    mfmaStep(NT - 1);

    // ---- epilogue: LDS transpose, 128B-contiguous NT stores, 4-way rep ----
    const int rbase = (l >> 4) * 4;
    const int cbase = l & 15;
    float* outm = outF + (size_t)mm * ((size_t)B_ * NH_ * V_ * D_);
    __syncthreads();
    float* scr = (float*)(smem + (size_t)w * 16384);
    const int nb = n0 + wc * 64;
    const int sh = nb >> 7;
    const int db = nb & 127;
#pragma unroll
    for (int p = 0; p < 2; ++p) {
#pragma unroll
        for (int fm = 0; fm < 8; ++fm)
#pragma unroll
            for (int fq = 0; fq < 2; ++fq) {
                const int fn = 2 * p + fq;
#pragma unroll
                for (int j = 0; j < 4; ++j) {
                    const int r = fm * 16 + rbase + j;
                    const int c = fq * 16 + cbase;
                    scr[r * 32 + (c ^ (((r >> 2) & 1) << 4))] = acc[fm][fn][j];
                }
            }
        const int c4   = (l & 7) * 4;
        const int colg = p * 32 + c4;
        f32x4 bv4;
#pragma unroll
        for (int q = 0; q < 4; ++q)
            bv4[q] = bias[(size_t)v * NDIM + nb + colg + q];
#pragma unroll
        for (int i = 0; i < 16; ++i) {
            const int r = i * 8 + (l >> 3);
            f32x4 val = *(const f32x4*)&scr[r * 32 + (c4 ^ (((r >> 2) & 1) << 4))];
#pragma unroll
            for (int q = 0; q < 4; ++q) val[q] += bv4[q];
            const int mr = m0 + wr * 128 + r;
            float* pp = outm + (size_t)mr * (NH_ * V_ * D_)
                             + (size_t)(sh * 4) * (V_ * D_)
                             + (size_t)v * D_ + db + colg;
            __builtin_nontemporal_store(val, (f32x4*)(pp));
            __builtin_nontemporal_store(val, (f32x4*)(pp + V_ * D_));
            __builtin_nontemporal_store(val, (f32x4*)(pp + 2 * V_ * D_));
            __builtin_nontemporal_store(val, (f32x4*)(pp + 3 * V_ * D_));
        }
    }
}

// ---------------------------------------------------------------------------
__global__ void tail_kernel(const float* __restrict__ af, float* __restrict__ out)
{
    out[0] = af[0];
}

// ---------------------------------------------------------------------------
extern "C" void kernel_launch(void* const* d_in, const int* in_sizes, int n_in,
                              void* d_out, int out_size, void* d_ws, size_t ws_size,
                              hipStream_t stream)
{
    const float* prefix = (const float*)d_in[0];
    const float* W1[2]  = {(const float*)d_in[1], (const float*)d_in[7]};
    const float* b1[2]  = {(const float*)d_in[2], (const float*)d_in[8]};
    const float* W2[2]  = {(const float*)d_in[3], (const float*)d_in[9]};
    const float* b2[2]  = {(const float*)d_in[4], (const float*)d_in[10]};
    const float* W3[2]  = {(const float*)d_in[5], (const float*)d_in[11]};
    const float* b3[2]  = {(const float*)d_in[6], (const float*)d_in[12]};
    const float* afac   = (const float*)d_in[13];

    // workspace: h2[2] = 2 x 128 MiB (h1 no longer materialized)
    bf16* h2a = (bf16*)d_ws;
    bf16* h2b = (bf16*)((char*)d_ws + (size_t)134217728);
    float* outp = (float*)d_out;

    // h2 = tanh(tanh(prefix.W1+b1) @ W2 + b2), h1 fused, both m, one launch
    gemm1_f<<<dim3(16, 4, 32), 512, 0, stream>>>(
        prefix, W1[0], b1[0], W1[1], b1[1],
        W2[0], W2[1], b2[0], b2[1], h2a, h2b);
    // out = h2 @ W3 + b3, keys+values in one 512-block launch
    gemm2_k<<<dim3(4, 4, 32), 512, 0, stream>>>(
        h2a, h2b, W3[0], W3[1], b3[0], b3[1], outp);
    tail_kernel<<<1, 1, 0, stream>>>(afac, outp + (size_t)2 * B_ * NH_ * V_ * D_);
}

// Round 16
// 930.203 us; speedup vs baseline: 4.0635x; 1.0960x over previous
//
#include <hip/hip_runtime.h>
#include <hip/hip_bf16.h>
#include <cstdint>

// Problem constants
#define B_   1024
#define V_   16
#define NH_  32
#define SH_  8
#define D_   128
#define KV_  1024
#define H_   4096

typedef __bf16 bf16;
typedef bf16  bf16x8 __attribute__((ext_vector_type(8)));
typedef float f32x2  __attribute__((ext_vector_type(2)));
typedef float f32x4  __attribute__((ext_vector_type(4)));

#define VMCNT(n) asm volatile("s_waitcnt vmcnt(" #n ")" ::: "memory")
#define LGKM0()  asm volatile("s_waitcnt lgkmcnt(0)" ::: "memory")

// async global->LDS, 16B per lane. LDS dest is wave-uniform base + lane*16.
__device__ __forceinline__ void gl2lds16(const void* g, void* l) {
    __builtin_amdgcn_global_load_lds((const __attribute__((address_space(1))) void*)g,
                                     (__attribute__((address_space(3))) void*)l,
                                     16, 0, 0);
}

// ---------------------------------------------------------------------------
// K1: h1[m][v][b][k] = tanh(prefix[b][v] * W1m[v][k] + b1m[v][k])  (bf16)
// ---------------------------------------------------------------------------
__global__ __launch_bounds__(256)
void h1_kernel(const float* __restrict__ prefix,
               const float* __restrict__ W1a, const float* __restrict__ b1a,
               const float* __restrict__ W1b, const float* __restrict__ b1b,
               bf16* __restrict__ h1)
{
    int gid = blockIdx.x * 256 + threadIdx.x;   // 2*V*B*KV/8 = 4M threads
    int k8  = gid & 127;                        // KV_/8 = 128
    int b   = (gid >> 7) & 1023;
    int vm  = gid >> 17;                        // 0..31
    int v   = vm & 15;
    const float* W1 = (vm >> 4) ? W1b : W1a;
    const float* b1 = (vm >> 4) ? b1b : b1a;
    float x = prefix[b * V_ + v];
    const float* wp = W1 + (size_t)v * KV_ + k8 * 8;
    const float* bp = b1 + (size_t)v * KV_ + k8 * 8;
    f32x4 w0 = *(const f32x4*)wp,       w1 = *(const f32x4*)(wp + 4);
    f32x4 q0 = *(const f32x4*)bp,       q1 = *(const f32x4*)(bp + 4);
    bf16x8 o;
#pragma unroll
    for (int j = 0; j < 4; ++j) o[j]     = (bf16)tanhf(fmaf(x, w0[j], q0[j]));
#pragma unroll
    for (int j = 0; j < 4; ++j) o[4 + j] = (bf16)tanhf(fmaf(x, w1[j], q1[j]));
    *(bf16x8*)(h1 + (size_t)gid * 8) = o;
}

// ---------------------------------------------------------------------------
// K2: GEMM with 4-PHASE interleaved K-step (m201-style T3/T4/T5 port).
//   C[m][v] = A_m[v] (1024 x KDIM bf16) * Bf_m[v] ([KDIM][NDIM] fp32)
// MODE 0: tanh(C+bias) -> bf16 h2, LDS-transposed full-line NT stores.
// MODE 1: C+bias -> fp32 scatter to [B,NH,V,D] (+m), 4-way head rep.
//
// Geometry (R12-proven): 256x256 tile, 512 thr, 8 waves (2m x 4n),
// 128x64 out/wave, acc[8][4], BK=64, LDS 128K (A dbuf 2x32K, B dbuf 2x32K),
// 1 block/CU, R9 decode (XCD-chunked bijective swizzle, m slowest).
//
// Round-16 change: the single-MFMA-phase step (MfmaUtil 25%, 3x off the
// ~2700cyc/step floor) becomes 4 phases of 16 MFMA each (kk x fm-half):
//   p0: issue br[0..7](kt+1) | ds_read bfv(kk0)+af(kk0,fm0-3) | bar |
//       setprio1 16 MFMA setprio0 | bar
//   p1: issue br[8..15] + 4x gl2lds A(kt+1) | af(kk0,fm4-7) | bar | MFMA | bar
//   p2: ds_read bfv(kk1)+af(kk1,fm0-3) | bar | MFMA | bar
//   p3: af(kk1,fm4-7) | VMCNT(4) retire br -> writeB(nxt) | bar | MFMA |
//       VMCNT(0) LGKM0 | bar (publish)
// br issued before gl2lds (older) so VMCNT(4) retires exactly the 16 br.
// No vmcnt(0) on just-issued loads: br ~3 phases in flight, gl2lds ~2.5.
// ---------------------------------------------------------------------------
template<int MODE, int KDIM, int NDIM>
__global__ __launch_bounds__(512)
void gemm_p4(const bf16* __restrict__ A0, const bf16* __restrict__ A1,
             const float* __restrict__ Bf0, const float* __restrict__ Bf1,
             const float* __restrict__ bias0, const float* __restrict__ bias1,
             bf16* __restrict__ outB0, bf16* __restrict__ outB1,
             float* __restrict__ outF)
{
    // aBuf: 2 x 32KB at [0, 65536); bBuf: 2 x 32KB at [65536, 131072)
    __shared__ __align__(16) char smem[131072];

    constexpr int NX  = NDIM / 256;     // n-blocks per v
    constexpr int NMB = 4;              // m-blocks per v
    constexpr int NXY = NX * NMB;       // blocks per v
    const int lin = blockIdx.x + NX * blockIdx.y + NXY * blockIdx.z;
    constexpr int NWG = NXY * 32;       // both m
    constexpr int CHK = NWG / 8;        // NWG % 8 == 0 (bijective swizzle)
    const int swz = (lin & 7) * CHK + (lin >> 3);
    const int mm  = swz / (NXY * 16);           // encoder index 0/1
    const int r2  = swz - mm * (NXY * 16);
    const int v   = r2 / NXY;
    const int rem = r2 - v * NXY;
    const int m0  = (rem / NX) * 256;           // m slower than n (R9)
    const int n0  = (rem - (rem / NX) * NX) * 256;

    const bf16*  Abase = mm ? A1 : A0;
    const float* Bbase = mm ? Bf1 : Bf0;
    const float* bias  = mm ? bias1 : bias0;

    const int t  = threadIdx.x;
    const int l  = t & 63;
    const int w  = t >> 6;          // wave id 0..7
    const int wr = w >> 2;          // wave row 0..1 (128 rows each)
    const int wc = w & 3;           // wave col 0..3 (64 cols each)
    constexpr int NT = KDIM / 64;
    static_assert(NT >= 4, "NT >= 4");

    const bf16*  Av = Abase + (size_t)v * 1024 * KDIM + (size_t)m0 * KDIM;
    const float* Bv = Bbase + (size_t)v * KDIM * NDIM + n0;

    f32x4 acc[8][4];
#pragma unroll
    for (int i = 0; i < 8; ++i)
#pragma unroll
        for (int j = 0; j < 4; ++j) acc[i][j] = f32x4{0.f, 0.f, 0.f, 0.f};

    // B staging: thread t covers n = 2*(t&127)+{0,1}, k-rows (t>>7)*16..+15
    const float* bptr = Bv + (size_t)((t >> 7) * 16) * NDIM + 2 * (t & 127);
    f32x2 br[16];

    auto loadBRh = [&](int ktile, int h) {      // half h: k-rows h*8..h*8+7
        const float* np = bptr + (size_t)ktile * 64 * NDIM;
#pragma unroll
        for (int j = 0; j < 8; ++j)
            br[h * 8 + j] = *(const f32x2*)(np + (size_t)(h * 8 + j) * NDIM);
    };
    auto stageA = [&](int ktile, int ab) {
#pragma unroll
        for (int i = 0; i < 4; ++i) {
            const int off = t + i * 512;            // 0..2047 (16B chunks)
            const int row = off >> 3;               // 0..255
            const int gc  = (off & 7) ^ ((row >> 1) & 7);
            gl2lds16(Av + (size_t)row * KDIM + ktile * 64 + gc * 8,
                     smem + (size_t)ab * 32768 + (size_t)off * 16);
        }
    };
    auto writeB = [&](int bb) {
        bf16* bN = (bf16*)(smem + 65536 + (size_t)bb * 32768);
#pragma unroll
        for (int i = 0; i < 2; ++i)
#pragma unroll
            for (int h = 0; h < 2; ++h) {
                bf16x8 pk;
#pragma unroll
                for (int jj = 0; jj < 8; ++jj) pk[jj] = (bf16)br[h * 8 + jj][i];
                const int n  = 2 * (t & 127) + i;               // 0..255
                const int ch = ((t >> 7) * 2 + h) ^ (t & 7);    // swizzled slot
                *(bf16x8*)(bN + (size_t)n * 64 + ch * 8) = pk;
            }
    };

    // ---- prologue: stage tile 0 (as R12) ----
    loadBRh(0, 0); loadBRh(0, 1);
    stageA(0, 0);
    VMCNT(4);                       // retire br(0); A(0) still flying
    writeB(0);
    VMCNT(0);                       // A(0) done
    LGKM0();
    __builtin_amdgcn_s_barrier();

    // ---- main loop: 4 phases x 16 MFMA per K-step ----
    const int kq = l >> 4;          // k-quarter 0..3
    const int lm = l & 15;
    for (int kt = 0; kt < NT; ++kt) {
        const int cur = kt & 1, nxt = cur ^ 1;
        const bool more = (kt + 1 < NT);
        const bf16* aC = (const bf16*)(smem + (size_t)cur * 32768);
        const bf16* bC = (const bf16*)(smem + 65536 + (size_t)cur * 32768);

        bf16x8 af[4], bfv[4];

        // ---------- p0: br half 0 | bfv(kk0) + af(kk0, fm0-3) ----------
        if (more) loadBRh(kt + 1, 0);
#pragma unroll
        for (int f = 0; f < 4; ++f) {
            const int nr = wc * 64 + f * 16 + lm;
            const int cb = kq ^ ((nr >> 1) & 7);
            bfv[f] = *(const bf16x8*)(bC + (size_t)nr * 64 + cb * 8);
        }
#pragma unroll
        for (int f = 0; f < 4; ++f) {
            const int mr = wr * 128 + f * 16 + lm;
            const int ca = kq ^ ((mr >> 1) & 7);
            af[f] = *(const bf16x8*)(aC + (size_t)mr * 64 + ca * 8);
        }
        __builtin_amdgcn_s_barrier();
        __builtin_amdgcn_s_setprio(1);
#pragma unroll
        for (int fm = 0; fm < 4; ++fm)
#pragma unroll
            for (int fn = 0; fn < 4; ++fn)
                acc[fm][fn] = __builtin_amdgcn_mfma_f32_16x16x32_bf16(
                    af[fm], bfv[fn], acc[fm][fn], 0, 0, 0);
        __builtin_amdgcn_s_setprio(0);
        __builtin_amdgcn_s_barrier();

        // ---------- p1: br half 1 + gl2lds A(kt+1) | af(kk0, fm4-7) ----------
        if (more) { loadBRh(kt + 1, 1); stageA(kt + 1, nxt); }
#pragma unroll
        for (int f = 0; f < 4; ++f) {
            const int mr = wr * 128 + (4 + f) * 16 + lm;
            const int ca = kq ^ ((mr >> 1) & 7);
            af[f] = *(const bf16x8*)(aC + (size_t)mr * 64 + ca * 8);
        }
        __builtin_amdgcn_s_barrier();
        __builtin_amdgcn_s_setprio(1);
#pragma unroll
        for (int fm = 0; fm < 4; ++fm)
#pragma unroll
            for (int fn = 0; fn < 4; ++fn)
                acc[4 + fm][fn] = __builtin_amdgcn_mfma_f32_16x16x32_bf16(
                    af[fm], bfv[fn], acc[4 + fm][fn], 0, 0, 0);
        __builtin_amdgcn_s_setprio(0);
        __builtin_amdgcn_s_barrier();

        // ---------- p2: bfv(kk1) + af(kk1, fm0-3) ----------
#pragma unroll
        for (int f = 0; f < 4; ++f) {
            const int nr = wc * 64 + f * 16 + lm;
            const int cb = (4 + kq) ^ ((nr >> 1) & 7);
            bfv[f] = *(const bf16x8*)(bC + (size_t)nr * 64 + cb * 8);
        }
#pragma unroll
        for (int f = 0; f < 4; ++f) {
            const int mr = wr * 128 + f * 16 + lm;
            const int ca = (4 + kq) ^ ((mr >> 1) & 7);
            af[f] = *(const bf16x8*)(aC + (size_t)mr * 64 + ca * 8);
        }
        __builtin_amdgcn_s_barrier();
        __builtin_amdgcn_s_setprio(1);
#pragma unroll
        for (int fm = 0; fm < 4; ++fm)
#pragma unroll
            for (int fn = 0; fn < 4; ++fn)
                acc[fm][fn] = __builtin_amdgcn_mfma_f32_16x16x32_bf16(
                    af[fm], bfv[fn], acc[fm][fn], 0, 0, 0);
        __builtin_amdgcn_s_setprio(0);
        __builtin_amdgcn_s_barrier();

        // ---------- p3: af(kk1, fm4-7) | retire br, writeB | publish ----------
#pragma unroll
        for (int f = 0; f < 4; ++f) {
            const int mr = wr * 128 + (4 + f) * 16 + lm;
            const int ca = (4 + kq) ^ ((mr >> 1) & 7);
            af[f] = *(const bf16x8*)(aC + (size_t)mr * 64 + ca * 8);
        }
        if (more) {
            VMCNT(4);               // retire the 16 br (older than gl2lds)
            writeB(nxt);            // B(kt+1) -> bBuf[nxt] (not read this step)
        }
        __builtin_amdgcn_s_barrier();
        __builtin_amdgcn_s_setprio(1);
#pragma unroll
        for (int fm = 0; fm < 4; ++fm)
#pragma unroll
            for (int fn = 0; fn < 4; ++fn)
                acc[4 + fm][fn] = __builtin_amdgcn_mfma_f32_16x16x32_bf16(
                    af[fm], bfv[fn], acc[4 + fm][fn], 0, 0, 0);
        __builtin_amdgcn_s_setprio(0);
        if (more) { VMCNT(0); }     // gl2lds A(kt+1) done (issued ~3 phases ago)
        LGKM0();                    // B ds_writes visible
        __builtin_amdgcn_s_barrier();   // publish tiles kt+1
    }

    // ---- epilogue. C/D frag: col = lane&15, row = (lane>>4)*4 + reg ----
    const int rbase = (l >> 4) * 4;
    const int cbase = l & 15;
    if (MODE == 0) {
        bf16* outB = mm ? outB1 : outB0;
        __syncthreads();   // main-loop LDS reads done before scratch reuse
        bf16* scr = (bf16*)(smem + (size_t)w * 16384);   // [128][64]
#pragma unroll
        for (int fn = 0; fn < 4; ++fn) {
            const int c  = fn * 16 + cbase;              // 0..63
            const float bv = bias[(size_t)v * NDIM + n0 + wc * 64 + c];
#pragma unroll
            for (int fm = 0; fm < 8; ++fm)
#pragma unroll
                for (int j = 0; j < 4; ++j) {
                    const int r = fm * 16 + rbase + j;   // 0..127
                    scr[r * 64 + (c ^ (((r >> 2) & 3) << 4))] =
                        (bf16)tanhf(acc[fm][fn][j] + bv);
                }
        }
        const int c8 = (l & 7) * 8;                      // lane's 8-col group
#pragma unroll
        for (int i = 0; i < 16; ++i) {
            const int r  = i * 8 + (l >> 3);             // 0..127
            bf16x8 val = *(const bf16x8*)&scr[r * 64 + (c8 ^ (((r >> 2) & 3) << 4))];
            const int mr = m0 + wr * 128 + r;
            const int nc = n0 + wc * 64 + c8;
            __builtin_nontemporal_store(val,
                (bf16x8*)(outB + (size_t)v * 1024 * NDIM + (size_t)mr * NDIM + nc));
        }
    } else {
        float* outm = outF + (size_t)mm * ((size_t)B_ * NH_ * V_ * D_);
        __syncthreads();   // main-loop LDS reads done before scratch reuse
        float* scr = (float*)(smem + (size_t)w * 16384);
        const int nb = n0 + wc * 64;     // wave col base (multiple of 64)
        const int sh = nb >> 7;          // slider head
        const int db = nb & 127;         // 0 or 64
#pragma unroll
        for (int p = 0; p < 2; ++p) {
#pragma unroll
            for (int fm = 0; fm < 8; ++fm)
#pragma unroll
                for (int fq = 0; fq < 2; ++fq) {
                    const int fn = 2 * p + fq;
#pragma unroll
                    for (int j = 0; j < 4; ++j) {
                        const int r = fm * 16 + rbase + j;      // 0..127
                        const int c = fq * 16 + cbase;          // 0..31
                        scr[r * 32 + (c ^ (((r >> 2) & 1) << 4))] = acc[fm][fn][j];
                    }
                }
            const int c4   = (l & 7) * 4;
            const int colg = p * 32 + c4;    // col within wave's 64-col strip
            f32x4 bv4;
#pragma unroll
            for (int q = 0; q < 4; ++q)
                bv4[q] = bias[(size_t)v * NDIM + nb + colg + q];
#pragma unroll
            for (int i = 0; i < 16; ++i) {
                const int r = i * 8 + (l >> 3);                 // 0..127
                f32x4 val = *(const f32x4*)&scr[r * 32 + (c4 ^ (((r >> 2) & 1) << 4))];
#pragma unroll
                for (int q = 0; q < 4; ++q) val[q] += bv4[q];
                const int mr = m0 + wr * 128 + r;
                float* pp = outm + (size_t)mr * (NH_ * V_ * D_)
                                 + (size_t)(sh * 4) * (V_ * D_)
                                 + (size_t)v * D_ + db + colg;
                __builtin_nontemporal_store(val, (f32x4*)(pp));
                __builtin_nontemporal_store(val, (f32x4*)(pp + V_ * D_));
                __builtin_nontemporal_store(val, (f32x4*)(pp + 2 * V_ * D_));
                __builtin_nontemporal_store(val, (f32x4*)(pp + 3 * V_ * D_));
            }
        }
    }
}

// ---------------------------------------------------------------------------
__global__ void tail_kernel(const float* __restrict__ af, float* __restrict__ out)
{
    out[0] = af[0];
}

// ---------------------------------------------------------------------------
extern "C" void kernel_launch(void* const* d_in, const int* in_sizes, int n_in,
                              void* d_out, int out_size, void* d_ws, size_t ws_size,
                              hipStream_t stream)
{
    const float* prefix = (const float*)d_in[0];
    const float* W1[2]  = {(const float*)d_in[1], (const float*)d_in[7]};
    const float* b1[2]  = {(const float*)d_in[2], (const float*)d_in[8]};
    const float* W2[2]  = {(const float*)d_in[3], (const float*)d_in[9]};
    const float* b2[2]  = {(const float*)d_in[4], (const float*)d_in[10]};
    const float* W3[2]  = {(const float*)d_in[5], (const float*)d_in[11]};
    const float* b3[2]  = {(const float*)d_in[6], (const float*)d_in[12]};
    const float* afac   = (const float*)d_in[13];

    // workspace: h1[2] = 2x32MiB, h2[2] = 2x128MiB  (ws is ~2.1 GB)
    bf16* h1  = (bf16*)d_ws;                                   // [m][v][b][k]
    bf16* h2a = (bf16*)((char*)d_ws + (size_t)67108864);
    bf16* h2b = (bf16*)((char*)d_ws + (size_t)67108864 + (size_t)134217728);
    float* outp = (float*)d_out;

    // h1 for both encoders
    h1_kernel<<<16384, 256, 0, stream>>>(prefix, W1[0], b1[0], W1[1], b1[1], h1);
    // h2 = tanh(h1 @ W2 + b2), both m in one 2048-block launch
    gemm_p4<0, 1024, 4096><<<dim3(16, 4, 32), 512, 0, stream>>>(
        h1, h1 + (size_t)16777216, W2[0], W2[1], b2[0], b2[1],
        h2a, h2b, nullptr);
    // out = h2 @ W3 + b3, keys+values in one 512-block launch
    gemm_p4<1, 4096, 1024><<<dim3(4, 4, 32), 512, 0, stream>>>(
        h2a, h2b, W3[0], W3[1], b3[0], b3[1],
        nullptr, nullptr, outp);
    tail_kernel<<<1, 1, 0, stream>>>(afac, outp + (size_t)2 * B_ * NH_ * V_ * D_);
}

// Round 17
// 868.361 us; speedup vs baseline: 4.3529x; 1.0712x over previous
//
#include <hip/hip_runtime.h>
#include <hip/hip_bf16.h>
#include <cstdint>

// Problem constants
#define B_   1024
#define V_   16
#define NH_  32
#define SH_  8
#define D_   128
#define KV_  1024
#define H_   4096

typedef __bf16 bf16;
typedef bf16  bf16x8 __attribute__((ext_vector_type(8)));
typedef float f32x2  __attribute__((ext_vector_type(2)));
typedef float f32x4  __attribute__((ext_vector_type(4)));

#define VMCNT(n) asm volatile("s_waitcnt vmcnt(" #n ")" ::: "memory")
#define LGKM0()  asm volatile("s_waitcnt lgkmcnt(0)" ::: "memory")

// async global->LDS, 16B per lane. LDS dest is wave-uniform base + lane*16.
__device__ __forceinline__ void gl2lds16(const void* g, void* l) {
    __builtin_amdgcn_global_load_lds((const __attribute__((address_space(1))) void*)g,
                                     (__attribute__((address_space(3))) void*)l,
                                     16, 0, 0);
}

// ---------------------------------------------------------------------------
// K1: h1[m][v][b][k] = tanh(prefix[b][v] * W1m[v][k] + b1m[v][k])  (bf16)
// Both encoders (m=0 key, m=1 value) in one launch.
// ---------------------------------------------------------------------------
__global__ __launch_bounds__(256)
void h1_kernel(const float* __restrict__ prefix,
               const float* __restrict__ W1a, const float* __restrict__ b1a,
               const float* __restrict__ W1b, const float* __restrict__ b1b,
               bf16* __restrict__ h1)
{
    int gid = blockIdx.x * 256 + threadIdx.x;   // 2*V*B*KV/8 = 4M threads
    int k8  = gid & 127;                        // KV_/8 = 128
    int b   = (gid >> 7) & 1023;
    int vm  = gid >> 17;                        // 0..31
    int v   = vm & 15;
    const float* W1 = (vm >> 4) ? W1b : W1a;
    const float* b1 = (vm >> 4) ? b1b : b1a;
    float x = prefix[b * V_ + v];
    const float* wp = W1 + (size_t)v * KV_ + k8 * 8;
    const float* bp = b1 + (size_t)v * KV_ + k8 * 8;
    f32x4 w0 = *(const f32x4*)wp,       w1 = *(const f32x4*)(wp + 4);
    f32x4 q0 = *(const f32x4*)bp,       q1 = *(const f32x4*)(bp + 4);
    bf16x8 o;
#pragma unroll
    for (int j = 0; j < 4; ++j) o[j]     = (bf16)tanhf(fmaf(x, w0[j], q0[j]));
#pragma unroll
    for (int j = 0; j < 4; ++j) o[4 + j] = (bf16)tanhf(fmaf(x, w1[j], q1[j]));
    *(bf16x8*)(h1 + (size_t)gid * 8) = o;
}

// ---------------------------------------------------------------------------
// K2: pipelined GEMM, fused B-transpose+fp32->bf16, both m in one launch.
//   C[m][v] = A_m[v] (1024 x KDIM bf16) * Bf_m[v] ([KDIM][NDIM] fp32)
// MODE 0: out = tanh(C + bias) -> bf16 h2[m][v][1024][NDIM], via per-wave
//         LDS transpose -> full-128B-line non-temporal stores.
// MODE 1: out = C + bias -> fp32 scattered to [B,NH,V,D] (+m offset), 4-way
//         head rep, LDS-transposed 128B-contiguous non-temporal stores.
//
// 256x256 tile, 512 threads, 8 waves (2m x 4n), 128x64 out/wave, acc[8][4],
// BK=64. LDS 128KB (A dbuf 2x32K, B dbuf 2x32K) -> 1 block/CU, 8 waves.
// Decode (R9-proven): XCD-chunked bijective swizzle, m-index slowest, then
// v, then m0 slower than n0 within v. Both m merged into one launch.
// Steady step kt: loadBR(kt+1)[16] | stageA(kt+1)[4 gl2lds] | MFMA(kt)
//   | VMCNT(4) retire br | writeB(kt+1) | VMCNT(0) | LGKM0 | s_barrier.
// ---------------------------------------------------------------------------
template<int MODE, int KDIM, int NDIM>
__global__ __launch_bounds__(512)
void gemm_t2(const bf16* __restrict__ A0, const bf16* __restrict__ A1,
             const float* __restrict__ Bf0, const float* __restrict__ Bf1,
             const float* __restrict__ bias0, const float* __restrict__ bias1,
             bf16* __restrict__ outB0, bf16* __restrict__ outB1,
             float* __restrict__ outF)
{
    // aBuf: 2 x 32KB at [0, 65536); bBuf: 2 x 32KB at [65536, 131072)
    __shared__ __align__(16) char smem[131072];

    constexpr int NX  = NDIM / 256;     // n-blocks per v
    constexpr int NMB = 4;              // m-blocks per v
    constexpr int NXY = NX * NMB;       // blocks per v
    const int lin = blockIdx.x + NX * blockIdx.y + NXY * blockIdx.z;
    constexpr int NWG = NXY * 32;       // both m
    constexpr int CHK = NWG / 8;        // NWG % 8 == 0 (bijective swizzle)
    const int swz = (lin & 7) * CHK + (lin >> 3);
    const int mm  = swz / (NXY * 16);           // encoder index 0/1
    const int r2  = swz - mm * (NXY * 16);
    const int v   = r2 / NXY;
    const int rem = r2 - v * NXY;
    const int m0  = (rem / NX) * 256;           // m slower than n (R9)
    const int n0  = (rem - (rem / NX) * NX) * 256;

    const bf16*  Abase = mm ? A1 : A0;
    const float* Bbase = mm ? Bf1 : Bf0;
    const float* bias  = mm ? bias1 : bias0;

    const int t  = threadIdx.x;
    const int l  = t & 63;
    const int w  = t >> 6;          // wave id 0..7
    const int wr = w >> 2;          // wave row 0..1 (128 rows each)
    const int wc = w & 3;           // wave col 0..3 (64 cols each)
    constexpr int NT = KDIM / 64;
    static_assert(NT >= 4, "NT >= 4");

    const bf16*  Av = Abase + (size_t)v * 1024 * KDIM + (size_t)m0 * KDIM;
    const float* Bv = Bbase + (size_t)v * KDIM * NDIM + n0;

    f32x4 acc[8][4];
#pragma unroll
    for (int i = 0; i < 8; ++i)
#pragma unroll
        for (int j = 0; j < 4; ++j) acc[i][j] = f32x4{0.f, 0.f, 0.f, 0.f};

    // B staging: thread t covers n = 2*(t&127)+{0,1}, k-rows (t>>7)*16..+15
    const float* bptr = Bv + (size_t)((t >> 7) * 16) * NDIM + 2 * (t & 127);
    f32x2 br[16];

    auto loadBR = [&](int ktile) {
        const float* np = bptr + (size_t)ktile * 64 * NDIM;
#pragma unroll
        for (int j = 0; j < 16; ++j) br[j] = *(const f32x2*)(np + (size_t)j * NDIM);
    };
    auto stageA = [&](int ktile, int ab) {
#pragma unroll
        for (int i = 0; i < 4; ++i) {
            const int off = t + i * 512;            // 0..2047 (16B chunks)
            const int row = off >> 3;               // 0..255
            const int gc  = (off & 7) ^ ((row >> 1) & 7);
            gl2lds16(Av + (size_t)row * KDIM + ktile * 64 + gc * 8,
                     smem + (size_t)ab * 32768 + (size_t)off * 16);
        }
    };
    auto writeB = [&](int bb) {
        bf16* bN = (bf16*)(smem + 65536 + (size_t)bb * 32768);
#pragma unroll
        for (int i = 0; i < 2; ++i)
#pragma unroll
            for (int h = 0; h < 2; ++h) {
                bf16x8 pk;
#pragma unroll
                for (int jj = 0; jj < 8; ++jj) pk[jj] = (bf16)br[h * 8 + jj][i];
                const int n  = 2 * (t & 127) + i;               // 0..255
                const int ch = ((t >> 7) * 2 + h) ^ (t & 7);    // swizzled slot
                *(bf16x8*)(bN + (size_t)n * 64 + ch * 8) = pk;
            }
    };
    auto mfmaStep = [&](int kt) {
        const bf16* aC = (const bf16*)(smem + (size_t)(kt & 1) * 32768);
        const bf16* bC = (const bf16*)(smem + 65536 + (size_t)(kt & 1) * 32768);
#pragma unroll
        for (int kk = 0; kk < 2; ++kk) {
            bf16x8 af[8], bfv[4];
#pragma unroll
            for (int f = 0; f < 8; ++f) {
                const int mr = wr * 128 + f * 16 + (l & 15);
                const int ca = (kk * 4 + (l >> 4)) ^ ((mr >> 1) & 7);
                af[f] = *(const bf16x8*)(aC + (size_t)mr * 64 + ca * 8);
            }
#pragma unroll
            for (int f = 0; f < 4; ++f) {
                const int nr = wc * 64 + f * 16 + (l & 15);
                const int cb = (kk * 4 + (l >> 4)) ^ ((nr >> 1) & 7);
                bfv[f] = *(const bf16x8*)(bC + (size_t)nr * 64 + cb * 8);
            }
#pragma unroll
            for (int fm = 0; fm < 8; ++fm)
#pragma unroll
                for (int fn = 0; fn < 4; ++fn)
                    acc[fm][fn] = __builtin_amdgcn_mfma_f32_16x16x32_bf16(
                        af[fm], bfv[fn], acc[fm][fn], 0, 0, 0);
        }
    };

    // ---- prologue: stage tile 0 ----
    loadBR(0);
    stageA(0, 0);
    VMCNT(4);                       // retire br(0); A(0) still flying
    writeB(0);
    VMCNT(0);                       // A(0) done
    LGKM0();
    __builtin_amdgcn_s_barrier();

    // ---- main loop ----
    for (int kt = 0; kt < NT - 1; ++kt) {
        loadBR(kt + 1);                 // 16 loads, fly under MFMA
        stageA(kt + 1, (kt + 1) & 1);   // 4 gl2lds, fly under MFMA
        mfmaStep(kt);                   // ~64 MFMAs
        VMCNT(4);                       // retire br(kt+1); A(kt+1) may fly
        writeB((kt + 1) & 1);
        VMCNT(0);                       // A(kt+1) done (issued a phase ago)
        LGKM0();
        __builtin_amdgcn_s_barrier();   // publish tiles kt+1
    }
    mfmaStep(NT - 1);                   // last step: compute only

    // ---- epilogue. C/D frag: col = lane&15, row = (lane>>4)*4 + reg ----
    const int rbase = (l >> 4) * 4;
    const int cbase = l & 15;
    if (MODE == 0) {
        bf16* outB = mm ? outB1 : outB0;
        __syncthreads();   // main-loop LDS reads done before scratch reuse
        // per-wave 128x64 bf16 scratch (16KB x 8 = 128KB). Write swizzled
        // (c ^ ((r>>2)&3)<<4): conflict-free. Read 8 consecutive cols/lane
        // -> 8 lanes cover a full 128B row -> full-line NT stores (kills
        // the 2.4x write RMW amplification of scalar-scatter stores).
        bf16* scr = (bf16*)(smem + (size_t)w * 16384);   // [128][64]
#pragma unroll
        for (int fn = 0; fn < 4; ++fn) {
            const int c  = fn * 16 + cbase;              // 0..63
            const float bv = bias[(size_t)v * NDIM + n0 + wc * 64 + c];
#pragma unroll
            for (int fm = 0; fm < 8; ++fm)
#pragma unroll
                for (int j = 0; j < 4; ++j) {
                    const int r = fm * 16 + rbase + j;   // 0..127
                    scr[r * 64 + (c ^ (((r >> 2) & 3) << 4))] =
                        (bf16)tanhf(acc[fm][fn][j] + bv);
                }
        }
        const int c8 = (l & 7) * 8;                      // lane's 8-col group
#pragma unroll
        for (int i = 0; i < 16; ++i) {
            const int r  = i * 8 + (l >> 3);             // 0..127
            bf16x8 val = *(const bf16x8*)&scr[r * 64 + (c8 ^ (((r >> 2) & 3) << 4))];
            const int mr = m0 + wr * 128 + r;
            const int nc = n0 + wc * 64 + c8;
            __builtin_nontemporal_store(val,
                (bf16x8*)(outB + (size_t)v * 1024 * NDIM + (size_t)mr * NDIM + nc));
        }
    } else {
        float* outm = outF + (size_t)mm * ((size_t)B_ * NH_ * V_ * D_);
        __syncthreads();   // main-loop LDS reads done before scratch reuse
        // per-wave 128x32 f32 scratch (16KB x 8 waves = 128KB), two 32-col
        // passes; swizzle (c ^ ((r>>2)&1)<<4): write 2-way (free), read full.
        float* scr = (float*)(smem + (size_t)w * 16384);
        const int nb = n0 + wc * 64;     // wave col base (multiple of 64)
        const int sh = nb >> 7;          // slider head
        const int db = nb & 127;         // 0 or 64
#pragma unroll
        for (int p = 0; p < 2; ++p) {
#pragma unroll
            for (int fm = 0; fm < 8; ++fm)
#pragma unroll
                for (int fq = 0; fq < 2; ++fq) {
                    const int fn = 2 * p + fq;
#pragma unroll
                    for (int j = 0; j < 4; ++j) {
                        const int r = fm * 16 + rbase + j;      // 0..127
                        const int c = fq * 16 + cbase;          // 0..31
                        scr[r * 32 + (c ^ (((r >> 2) & 1) << 4))] = acc[fm][fn][j];
                    }
                }
            const int c4   = (l & 7) * 4;
            const int colg = p * 32 + c4;    // col within wave's 64-col strip
            f32x4 bv4;
#pragma unroll
            for (int q = 0; q < 4; ++q)
                bv4[q] = bias[(size_t)v * NDIM + nb + colg + q];
#pragma unroll
            for (int i = 0; i < 16; ++i) {
                const int r = i * 8 + (l >> 3);                 // 0..127
                f32x4 val = *(const f32x4*)&scr[r * 32 + (c4 ^ (((r >> 2) & 1) << 4))];
#pragma unroll
                for (int q = 0; q < 4; ++q) val[q] += bv4[q];
                const int mr = m0 + wr * 128 + r;
                float* pp = outm + (size_t)mr * (NH_ * V_ * D_)
                                 + (size_t)(sh * 4) * (V_ * D_)
                                 + (size_t)v * D_ + db + colg;
                // out is write-only: non-temporal, don't evict W3/h2
                __builtin_nontemporal_store(val, (f32x4*)(pp));
                __builtin_nontemporal_store(val, (f32x4*)(pp + V_ * D_));
                __builtin_nontemporal_store(val, (f32x4*)(pp + 2 * V_ * D_));
                __builtin_nontemporal_store(val, (f32x4*)(pp + 3 * V_ * D_));
            }
        }
    }
}

// ---------------------------------------------------------------------------
__global__ void tail_kernel(const float* __restrict__ af, float* __restrict__ out)
{
    out[0] = af[0];
}

// ---------------------------------------------------------------------------
extern "C" void kernel_launch(void* const* d_in, const int* in_sizes, int n_in,
                              void* d_out, int out_size, void* d_ws, size_t ws_size,
                              hipStream_t stream)
{
    const float* prefix = (const float*)d_in[0];
    const float* W1[2]  = {(const float*)d_in[1], (const float*)d_in[7]};
    const float* b1[2]  = {(const float*)d_in[2], (const float*)d_in[8]};
    const float* W2[2]  = {(const float*)d_in[3], (const float*)d_in[9]};
    const float* b2[2]  = {(const float*)d_in[4], (const float*)d_in[10]};
    const float* W3[2]  = {(const float*)d_in[5], (const float*)d_in[11]};
    const float* b3[2]  = {(const float*)d_in[6], (const float*)d_in[12]};
    const float* afac   = (const float*)d_in[13];

    // workspace: h1[2] = 2x32MiB, h2[2] = 2x128MiB  (ws is ~2.1 GB)
    bf16* h1  = (bf16*)d_ws;                                   // [m][v][b][k]
    bf16* h2a = (bf16*)((char*)d_ws + (size_t)67108864);
    bf16* h2b = (bf16*)((char*)d_ws + (size_t)67108864 + (size_t)134217728);
    float* outp = (float*)d_out;

    // h1 for both encoders
    h1_kernel<<<16384, 256, 0, stream>>>(prefix, W1[0], b1[0], W1[1], b1[1], h1);
    // h2 = tanh(h1 @ W2 + b2), both m in one 2048-block launch
    gemm_t2<0, 1024, 4096><<<dim3(16, 4, 32), 512, 0, stream>>>(
        h1, h1 + (size_t)16777216, W2[0], W2[1], b2[0], b2[1],
        h2a, h2b, nullptr);
    // out = h2 @ W3 + b3, keys+values in one 512-block launch
    gemm_t2<1, 4096, 1024><<<dim3(4, 4, 32), 512, 0, stream>>>(
        h2a, h2b, W3[0], W3[1], b3[0], b3[1],
        nullptr, nullptr, outp);
    tail_kernel<<<1, 1, 0, stream>>>(afac, outp + (size_t)2 * B_ * NH_ * V_ * D_);
}